// Round 1
// baseline (895.592 us; speedup 1.0000x reference)
//
#include <hip/hip_runtime.h>
#include <math.h>

#define SEQ_L 1024
#define DPAIR 128
#define DMSA 256
#define DSTATE 32
#define JT 32

// ws layout (float offsets)
#define WS_CB   0          // 1024*3, padded to 4096
#define WS_SN   4096       // 1024*32 = 32768
#define WS_LRB  36864      // 1024*128 = 131072
#define WS_RT   167936     // 1024*128 = 131072
#define WS_WDT  299008     // 36*128 = 4608
// total 303616 floats = 1.19 MB

// out layout (float offsets): msa_out, pair_out, state_n
#define OUT_MSA   0
#define OUT_PAIR  262144
#define OUT_STATE 134479872LL

__global__ __launch_bounds__(256) void k_pre(
    const float* __restrict__ state, const float* __restrict__ xyz,
    const float* __restrict__ W, const float* __restrict__ g_state,
    const float* __restrict__ b_state, const float* __restrict__ msa,
    const float* __restrict__ g_msa, const float* __restrict__ b_msa,
    float* __restrict__ ws, float* __restrict__ out)
{
    __shared__ float sp[4], sq[4];
    const int bid = blockIdx.x;
    const int t = threadIdx.x;

    if (bid < 128) {
        // state layernorm: 8 rows of 32 per block
        int r = bid * 8 + (t >> 5);
        int k = t & 31;
        float x = state[r * DSTATE + k];
        float s = x, q = x * x;
        #pragma unroll
        for (int m = 16; m >= 1; m >>= 1) { s += __shfl_xor(s, m, 32); q += __shfl_xor(q, m, 32); }
        float mean = s * (1.0f / 32.0f);
        float var = q * (1.0f / 32.0f) - mean * mean;
        float rs = rsqrtf(var + 1e-5f);
        float y = (x - mean) * rs * g_state[k] + b_state[k];
        ws[WS_SN + r * DSTATE + k] = y;
        out[OUT_STATE + r * DSTATE + k] = y;
    } else if (bid < 1152) {
        // msa layernorm: one row of 256 per block
        int row = bid - 128;
        float x = msa[row * DMSA + t];
        float s = x, q = x * x;
        #pragma unroll
        for (int m = 32; m >= 1; m >>= 1) { s += __shfl_xor(s, m, 64); q += __shfl_xor(q, m, 64); }
        int wv = t >> 6;
        if ((t & 63) == 0) { sp[wv] = s; sq[wv] = q; }
        __syncthreads();
        s = sp[0] + sp[1] + sp[2] + sp[3];
        q = sq[0] + sq[1] + sq[2] + sq[3];
        float mean = s * (1.0f / 256.0f);
        float var = q * (1.0f / 256.0f) - mean * mean;
        float rs = rsqrtf(var + 1e-5f);
        out[OUT_MSA + row * DMSA + t] = (x - mean) * rs * g_msa[t] + b_msa[t];
    } else if (bid < 1156) {
        // Cb from xyz: 1024 points
        int idx = (bid - 1152) * 256 + t;
        const float* p = xyz + idx * 9;
        float Nx = p[0], Ny = p[1], Nz = p[2];
        float Ax = p[3], Ay = p[4], Az = p[5];
        float Cx = p[6], Cy = p[7], Cz = p[8];
        float bx = Ax - Nx, by = Ay - Ny, bz = Az - Nz;
        float cx = Cx - Ax, cy = Cy - Ay, cz = Cz - Az;
        float ax = by * cz - bz * cy;
        float ay = bz * cx - bx * cz;
        float az = bx * cy - by * cx;
        ws[WS_CB + idx * 3 + 0] = -0.58273431f * ax + 0.56802827f * bx - 0.54067466f * cx + Ax;
        ws[WS_CB + idx * 3 + 1] = -0.58273431f * ay + 0.56802827f * by - 0.54067466f * cy + Ay;
        ws[WS_CB + idx * 3 + 2] = -0.58273431f * az + 0.56802827f * bz - 0.54067466f * cz + Az;
    } else {
        // W_d transpose: wdT[k*128+p] = W[p*100+k], 4608 elems
        int idx = (bid - 1156) * 256 + t;
        int k = idx >> 7, p = idx & 127;
        ws[WS_WDT + idx] = W[p * 100 + k];
    }
}

__global__ __launch_bounds__(128) void k_lr(
    const float* __restrict__ W, const float* __restrict__ b_proj,
    const float* __restrict__ b_pair, float* __restrict__ ws)
{
    __shared__ float s_sn[DSTATE];
    const int i = blockIdx.x;
    const int p = threadIdx.x;
    if (p < DSTATE) s_sn[p] = ws[WS_SN + i * DSTATE + p];
    __syncthreads();
    const float* wrow = W + p * 100;
    float l = 0.0f, r = 0.0f;
    #pragma unroll
    for (int k = 0; k < DSTATE; ++k) {
        float s = s_sn[k];
        l = fmaf(s, wrow[36 + k], l);
        r = fmaf(s, wrow[68 + k], r);
    }
    ws[WS_LRB + i * DPAIR + p] = l + b_proj[p] + b_pair[p];
    ws[WS_RT + i * DPAIR + p] = r;
}

__global__ __launch_bounds__(256) void k_main(
    const float* __restrict__ pair, const float* __restrict__ g_pair,
    const float* __restrict__ ws, float* __restrict__ out)
{
    __shared__ __align__(16) float s_wd[36 * 128];
    __shared__ __align__(16) float s_feats[JT * 36];
    __shared__ __align__(16) float s_right[JT * 128];
    __shared__ __align__(16) float s_lrb[128];
    __shared__ __align__(16) float s_g[128];
    __shared__ float s_D[JT];

    const int t = threadIdx.x;
    const int bid = blockIdx.x;
    const int i = bid >> 5;
    const int j0 = (bid & 31) * JT;

    // ---- stage LDS ----
    {
        const float4* wdT4 = (const float4*)(ws + WS_WDT);
        float4* s_wd4 = (float4*)s_wd;
        for (int idx = t; idx < 36 * 128 / 4; idx += 256) s_wd4[idx] = wdT4[idx];
        const float4* rt4 = (const float4*)(ws + WS_RT + (size_t)j0 * DPAIR);
        float4* s_right4 = (float4*)s_right;
        for (int idx = t; idx < JT * 128 / 4; idx += 256) s_right4[idx] = rt4[idx];
        if (t < 128) {
            s_lrb[t] = ws[WS_LRB + i * DPAIR + t];
            s_g[t] = g_pair[t];
        }
        if (t < JT) {
            const float* cb = ws + WS_CB;
            float dx = cb[i * 3 + 0] - cb[(j0 + t) * 3 + 0];
            float dy = cb[i * 3 + 1] - cb[(j0 + t) * 3 + 1];
            float dz = cb[i * 3 + 2] - cb[(j0 + t) * 3 + 2];
            float d2 = dx * dx + dy * dy + dz * dz;
            s_D[t] = sqrtf(fmaxf(d2, 1e-12f));
        }
    }
    __syncthreads();
    // feats: JT*36 rbf values
    for (int idx = t; idx < JT * 36; idx += 256) {
        int j = idx / 36;
        int k = idx - j * 36;
        float mu = 2.0f + (float)k * (20.0f / 35.0f);
        float u = (s_D[j] - mu) * 1.8f;   // 1/D_SIGMA = 36/20
        s_feats[idx] = __expf(-u * u);
    }
    __syncthreads();

    // ---- element phase ----
    const int lane = t & 63;
    const int wv = t >> 6;
    const int chq = lane & 31;              // channel-quad id, ch = 4*chq
    const int ch = chq << 2;
    const int jbase = wv * 8 + ((lane >> 5) << 2);  // 4 j's per lane

    const float4* p4 = (const float4*)(pair + ((size_t)i * SEQ_L + j0) * DPAIR);
    float4* o4 = (float4*)(out + OUT_PAIR + ((size_t)i * SEQ_L + j0) * DPAIR);

    // issue pair loads early (independent of the k-loop below)
    float4 pv[4];
    #pragma unroll
    for (int jj = 0; jj < 4; ++jj)
        pv[jj] = p4[(jbase + jj) * 32 + chq];

    // proj: acc[jj] = sum_k feats[j][k] * W_d[ch..ch+3][k]
    float4 acc[4];
    #pragma unroll
    for (int jj = 0; jj < 4; ++jj) acc[jj] = make_float4(0.f, 0.f, 0.f, 0.f);
    #pragma unroll
    for (int kq = 0; kq < 9; ++kq) {
        float4 w0 = *(const float4*)(s_wd + (4 * kq + 0) * 128 + ch);
        float4 w1 = *(const float4*)(s_wd + (4 * kq + 1) * 128 + ch);
        float4 w2 = *(const float4*)(s_wd + (4 * kq + 2) * 128 + ch);
        float4 w3 = *(const float4*)(s_wd + (4 * kq + 3) * 128 + ch);
        #pragma unroll
        for (int jj = 0; jj < 4; ++jj) {
            float4 f = *(const float4*)(s_feats + (jbase + jj) * 36 + 4 * kq);
            acc[jj].x = fmaf(f.x, w0.x, fmaf(f.y, w1.x, fmaf(f.z, w2.x, fmaf(f.w, w3.x, acc[jj].x))));
            acc[jj].y = fmaf(f.x, w0.y, fmaf(f.y, w1.y, fmaf(f.z, w2.y, fmaf(f.w, w3.y, acc[jj].y))));
            acc[jj].z = fmaf(f.x, w0.z, fmaf(f.y, w1.z, fmaf(f.z, w2.z, fmaf(f.w, w3.z, acc[jj].z))));
            acc[jj].w = fmaf(f.x, w0.w, fmaf(f.y, w1.w, fmaf(f.z, w2.w, fmaf(f.w, w3.w, acc[jj].w))));
        }
    }

    float4 g4 = *(const float4*)(s_g + ch);
    float4 lrb4 = *(const float4*)(s_lrb + ch);

    #pragma unroll
    for (int jj = 0; jj < 4; ++jj) {
        float4 v = pv[jj];
        float s = v.x + v.y + v.z + v.w;
        float q = fmaf(v.x, v.x, fmaf(v.y, v.y, fmaf(v.z, v.z, v.w * v.w)));
        #pragma unroll
        for (int m = 16; m >= 1; m >>= 1) { s += __shfl_xor(s, m, 32); q += __shfl_xor(q, m, 32); }
        float mean = s * (1.0f / 128.0f);
        float var = q * (1.0f / 128.0f) - mean * mean;
        float rs = rsqrtf(var + 1e-5f);
        float4 r4 = *(const float4*)(s_right + (jbase + jj) * 128 + ch);
        float tgx = rs * g4.x, tgy = rs * g4.y, tgz = rs * g4.z, tgw = rs * g4.w;
        float4 o;
        o.x = acc[jj].x + lrb4.x + r4.x + (v.x - mean) * tgx;
        o.y = acc[jj].y + lrb4.y + r4.y + (v.y - mean) * tgy;
        o.z = acc[jj].z + lrb4.z + r4.z + (v.z - mean) * tgz;
        o.w = acc[jj].w + lrb4.w + r4.w + (v.w - mean) * tgw;
        o4[(jbase + jj) * 32 + chq] = o;
    }
}

extern "C" void kernel_launch(void* const* d_in, const int* in_sizes, int n_in,
                              void* d_out, int out_size, void* d_ws, size_t ws_size,
                              hipStream_t stream) {
    // inputs: 0 seq, 1 msa, 2 pair, 3 xyz, 4 state, 5 W, 6 b_proj,
    //         7 g_state, 8 b_state, 9 g_pair, 10 b_pair, 11 g_msa, 12 b_msa
    const float* msa     = (const float*)d_in[1];
    const float* pair    = (const float*)d_in[2];
    const float* xyz     = (const float*)d_in[3];
    const float* state   = (const float*)d_in[4];
    const float* W       = (const float*)d_in[5];
    const float* b_proj  = (const float*)d_in[6];
    const float* g_state = (const float*)d_in[7];
    const float* b_state = (const float*)d_in[8];
    const float* g_pair  = (const float*)d_in[9];
    const float* b_pair  = (const float*)d_in[10];
    const float* g_msa   = (const float*)d_in[11];
    const float* b_msa   = (const float*)d_in[12];
    float* out = (float*)d_out;
    float* ws  = (float*)d_ws;

    k_pre<<<1174, 256, 0, stream>>>(state, xyz, W, g_state, b_state,
                                    msa, g_msa, b_msa, ws, out);
    k_lr<<<1024, 128, 0, stream>>>(W, b_proj, b_pair, ws);
    k_main<<<32768, 256, 0, stream>>>(pair, g_pair, ws, out);
}